// Round 1
// baseline (389.052 us; speedup 1.0000x reference)
//
#include <hip/hip_runtime.h>
#include <math.h>

#define ROWS_PER_BLOCK 16
#define NPAIRS 195
#define NTHREADS 256

// ---- compile-time pair table (matches reference _build_pairs) ----
struct PairTab { unsigned char i[NPAIRS]; unsigned char j[NPAIRS]; };

constexpr PairTab make_pairs() {
    PairTab t{};
    int n = 0;
    for (int a = 0; a < 20; ++a) {
        bool tip = (a == 4) || (a == 8) || (a == 12) || (a == 16) || (a == 19);
        int start = tip ? a + 1 : a + 2;
        for (int b = start; b < 21; ++b) {
            t.i[n] = (unsigned char)a;
            t.j[n] = (unsigned char)b;
            ++n;
        }
    }
    return t;
}

__constant__ PairTab PAIRS = make_pairs();

// in : [B, 63]  (21 landmarks x (x,y,z))
// out: [B, 258] = [copy of 63 | 195 pairwise 2D distances]
__global__ __launch_bounds__(NTHREADS)
void HandKineticLayer_18545668784560_kernel(const float* __restrict__ in,
                                            float* __restrict__ out,
                                            int B) {
    __shared__ float xy[ROWS_PER_BLOCK][42];  // 21 landmarks x (x,y) per row

    const int rowBase = blockIdx.x * ROWS_PER_BLOCK;
    const int t = threadIdx.x;
    const int nrows = min(ROWS_PER_BLOCK, B - rowBase);
    if (nrows <= 0) return;

    if (nrows == ROWS_PER_BLOCK) {
        // fast path: 252 x float4 = 16 rows * 63 floats, base is 16B-aligned
        const float4* __restrict__ in4 =
            reinterpret_cast<const float4*>(in + (size_t)rowBase * 63);
        if (t < 252) {
            float4 v = in4[t];
            const float vv[4] = {v.x, v.y, v.z, v.w};
            const int f = t * 4;
#pragma unroll
            for (int e = 0; e < 4; ++e) {
                const int g = f + e;
                const int row = g / 63;
                const int col = g - row * 63;
                out[(size_t)(rowBase + row) * 258 + col] = vv[e];
                const int c3 = col % 3;
                if (c3 != 2) xy[row][(col / 3) * 2 + c3] = vv[e];
            }
        }
    } else {
        // tail block: scalar guarded loads
        const int nelem = nrows * 63;
        for (int g = t; g < nelem; g += NTHREADS) {
            const float val = in[(size_t)rowBase * 63 + g];
            const int row = g / 63;
            const int col = g - row * 63;
            out[(size_t)(rowBase + row) * 258 + col] = val;
            const int c3 = col % 3;
            if (c3 != 2) xy[row][(col / 3) * 2 + c3] = val;
        }
    }

    __syncthreads();

    const int total = nrows * NPAIRS;
    for (int idx = t; idx < total; idx += NTHREADS) {
        const int row = idx / NPAIRS;
        const int p = idx - row * NPAIRS;
        const int i = PAIRS.i[p];
        const int j = PAIRS.j[p];
        const float dx = xy[row][i * 2]     - xy[row][j * 2];
        const float dy = xy[row][i * 2 + 1] - xy[row][j * 2 + 1];
        out[(size_t)(rowBase + row) * 258 + 63 + p] = sqrtf(dx * dx + dy * dy);
    }
}

extern "C" void kernel_launch(void* const* d_in, const int* in_sizes, int n_in,
                              void* d_out, int out_size, void* d_ws, size_t ws_size,
                              hipStream_t stream) {
    const float* in = (const float*)d_in[0];
    float* out = (float*)d_out;
    const int B = in_sizes[0] / 63;
    const int blocks = (B + ROWS_PER_BLOCK - 1) / ROWS_PER_BLOCK;
    hipLaunchKernelGGL(HandKineticLayer_18545668784560_kernel,
                       dim3(blocks), dim3(NTHREADS), 0, stream,
                       in, out, B);
}

// Round 3
// 350.319 us; speedup vs baseline: 1.1106x; 1.1106x over previous
//
#include <hip/hip_runtime.h>
#include <math.h>

#define ROWS_PER_BLOCK 16
#define NPAIRS 195
#define NTHREADS 256
#define ROW_OUT 258   // 63 copied + 195 distances

typedef float f32x4 __attribute__((ext_vector_type(4)));

// ---- compile-time pair table (matches reference _build_pairs) ----
struct PairTab { unsigned char i[NPAIRS]; unsigned char j[NPAIRS]; };

constexpr PairTab make_pairs() {
    PairTab t{};
    int n = 0;
    for (int a = 0; a < 20; ++a) {
        bool tip = (a == 4) || (a == 8) || (a == 12) || (a == 16) || (a == 19);
        int start = tip ? a + 1 : a + 2;
        for (int b = start; b < 21; ++b) {
            t.i[n] = (unsigned char)a;
            t.j[n] = (unsigned char)b;
            ++n;
        }
    }
    return t;
}

__constant__ PairTab PAIRS = make_pairs();

// in : [B, 63]  (21 landmarks x (x,y,z))
// out: [B, 258] = [copy of 63 | 195 pairwise 2D distances]
__global__ __launch_bounds__(NTHREADS)
void HandKineticLayer_18545668784560_kernel(const float* __restrict__ in,
                                            float* __restrict__ out,
                                            int B) {
    // Full output tile for this block: 16 rows x 258 floats = 16512 B.
    __shared__ __align__(16) float tile[ROWS_PER_BLOCK * ROW_OUT];

    const int rowBase = blockIdx.x * ROWS_PER_BLOCK;
    const int t = threadIdx.x;
    const int nrows = min(ROWS_PER_BLOCK, B - rowBase);
    if (nrows <= 0) return;

    // ---- phase 1: load input, scatter copy-through into LDS tile ----
    if (nrows == ROWS_PER_BLOCK) {
        // 252 x float4 = 16 rows * 63 floats; base 16B-aligned (16*63*4=4032B)
        const f32x4* __restrict__ in4 =
            reinterpret_cast<const f32x4*>(in + (size_t)rowBase * 63);
        if (t < 252) {
            const f32x4 v = __builtin_nontemporal_load(&in4[t]);
            const int f = t * 4;
#pragma unroll
            for (int e = 0; e < 4; ++e) {
                const int g = f + e;
                const int row = g / 63;
                const int col = g - row * 63;
                tile[row * ROW_OUT + col] = v[e];
            }
        }
    } else {
        const int nelem = nrows * 63;
        for (int g = t; g < nelem; g += NTHREADS) {
            const float val = in[(size_t)rowBase * 63 + g];
            const int row = g / 63;
            const int col = g - row * 63;
            tile[row * ROW_OUT + col] = val;
        }
    }

    __syncthreads();

    // ---- phase 2: 195 pairwise 2D distances per row, into LDS tile ----
    const int total = nrows * NPAIRS;
    for (int idx = t; idx < total; idx += NTHREADS) {
        const int row = idx / NPAIRS;          // magic-mul, cheap
        const int p = idx - row * NPAIRS;
        const int i = PAIRS.i[p];
        const int j = PAIRS.j[p];
        const float* __restrict__ r = &tile[row * ROW_OUT];
        const float dx = r[i * 3]     - r[j * 3];      // stride-3: conflict-free
        const float dy = r[i * 3 + 1] - r[j * 3 + 1];
        tile[row * ROW_OUT + 63 + p] = sqrtf(dx * dx + dy * dy);
    }

    __syncthreads();

    // ---- phase 3: stream the whole tile out, coalesced float4 ----
    if (nrows == ROWS_PER_BLOCK) {
        const f32x4* __restrict__ tl4 = reinterpret_cast<const f32x4*>(tile);
        f32x4* __restrict__ o4 =
            reinterpret_cast<f32x4*>(out + (size_t)rowBase * ROW_OUT);
        // 16*258/4 = 1032 float4 per block; wave writes 1 KiB contiguous
#pragma unroll
        for (int k = t; k < (ROWS_PER_BLOCK * ROW_OUT) / 4; k += NTHREADS) {
            __builtin_nontemporal_store(tl4[k], &o4[k]);
        }
    } else {
        const int nout = nrows * ROW_OUT;
        for (int k = t; k < nout; k += NTHREADS) {
            out[(size_t)rowBase * ROW_OUT + k] = tile[k];
        }
    }
}

extern "C" void kernel_launch(void* const* d_in, const int* in_sizes, int n_in,
                              void* d_out, int out_size, void* d_ws, size_t ws_size,
                              hipStream_t stream) {
    const float* in = (const float*)d_in[0];
    float* out = (float*)d_out;
    const int B = in_sizes[0] / 63;
    const int blocks = (B + ROWS_PER_BLOCK - 1) / ROWS_PER_BLOCK;
    hipLaunchKernelGGL(HandKineticLayer_18545668784560_kernel,
                       dim3(blocks), dim3(NTHREADS), 0, stream,
                       in, out, B);
}

// Round 4
// 283.686 us; speedup vs baseline: 1.3714x; 1.2349x over previous
//
#include <hip/hip_runtime.h>
#include <math.h>

#define ROWS_PER_BLOCK 16
#define NPAIRS 195
#define NTHREADS 256
#define ROW_OUT 258   // 63 copied + 195 distances
#define NLM 21

typedef float f32x4 __attribute__((ext_vector_type(4)));

// ---- compile-time pair table, packed as (i | j<<16) ----
struct CodeTab { unsigned int c[NPAIRS]; };

constexpr CodeTab make_codes() {
    CodeTab t{};
    int n = 0;
    for (int a = 0; a < 20; ++a) {
        bool tip = (a == 4) || (a == 8) || (a == 12) || (a == 16) || (a == 19);
        int start = tip ? a + 1 : a + 2;
        for (int b = start; b < 21; ++b) {
            t.c[n] = (unsigned int)a | ((unsigned int)b << 16);
            ++n;
        }
    }
    return t;
}

__constant__ CodeTab CODES = make_codes();

// in : [B, 63]  (21 landmarks x (x,y,z))
// out: [B, 258] = [copy of 63 | 195 pairwise 2D distances]
__global__ __launch_bounds__(NTHREADS)
void HandKineticLayer_18545668784560_kernel(const float* __restrict__ in,
                                            float* __restrict__ out,
                                            int B) {
    // Full output tile for this block: 16 rows x 258 floats = 16512 B.
    __shared__ __align__(16) float tile[ROWS_PER_BLOCK * ROW_OUT];
    // xy packed as float2 -> ds_read_b64 per landmark (8B aligned)
    __shared__ float2 xy2[ROWS_PER_BLOCK * NLM];

    const int rowBase = blockIdx.x * ROWS_PER_BLOCK;
    const int t = threadIdx.x;
    const int nrows = min(ROWS_PER_BLOCK, B - rowBase);
    if (nrows <= 0) return;

    // ---- phase 1: load input, scatter into tile (copy) + xy2 (x,y) ----
    if (nrows == ROWS_PER_BLOCK) {
        const f32x4* __restrict__ in4 =
            reinterpret_cast<const f32x4*>(in + (size_t)rowBase * 63);
        if (t < 252) {
            const f32x4 v = __builtin_nontemporal_load(&in4[t]);
            const int f = t * 4;
#pragma unroll
            for (int e = 0; e < 4; ++e) {
                const int g = f + e;
                const int row = g / 63;
                const int col = g - row * 63;
                tile[row * ROW_OUT + col] = v[e];
                const int lm = col / 3;
                const int c3 = col - lm * 3;
                if (c3 == 0) xy2[row * NLM + lm].x = v[e];
                else if (c3 == 1) xy2[row * NLM + lm].y = v[e];
            }
        }
    } else {
        const int nelem = nrows * 63;
        for (int g = t; g < nelem; g += NTHREADS) {
            const float val = in[(size_t)rowBase * 63 + g];
            const int row = g / 63;
            const int col = g - row * 63;
            tile[row * ROW_OUT + col] = val;
            const int lm = col / 3;
            const int c3 = col - lm * 3;
            if (c3 == 0) xy2[row * NLM + lm].x = val;
            else if (c3 == 1) xy2[row * NLM + lm].y = val;
        }
    }

    __syncthreads();

    // ---- phase 2: 195 pairwise 2D distances per row ----
    if (nrows == ROWS_PER_BLOCK) {
        // 16*195 = 3120 tasks; 13 fixed trips, unrolled for ILP
#pragma unroll
        for (int k = 0; k < 13; ++k) {
            const int idx = t + k * NTHREADS;
            if (idx < ROWS_PER_BLOCK * NPAIRS) {
                const int row = idx / NPAIRS;          // magic-mul
                const int p = idx - row * NPAIRS;
                const unsigned int c = CODES.c[p];     // 1 VMEM dword (L1-hot)
                const float2 a = xy2[row * NLM + (int)(c & 0xffu)];
                const float2 b = xy2[row * NLM + (int)(c >> 16)];
                const float dx = a.x - b.x;
                const float dy = a.y - b.y;
                tile[row * ROW_OUT + 63 + p] = sqrtf(dx * dx + dy * dy);
            }
        }
    } else {
        const int total = nrows * NPAIRS;
        for (int idx = t; idx < total; idx += NTHREADS) {
            const int row = idx / NPAIRS;
            const int p = idx - row * NPAIRS;
            const unsigned int c = CODES.c[p];
            const float2 a = xy2[row * NLM + (int)(c & 0xffu)];
            const float2 b = xy2[row * NLM + (int)(c >> 16)];
            const float dx = a.x - b.x;
            const float dy = a.y - b.y;
            tile[row * ROW_OUT + 63 + p] = sqrtf(dx * dx + dy * dy);
        }
    }

    __syncthreads();

    // ---- phase 3: stream the whole tile out, coalesced float4 ----
    if (nrows == ROWS_PER_BLOCK) {
        const f32x4* __restrict__ tl4 = reinterpret_cast<const f32x4*>(tile);
        f32x4* __restrict__ o4 =
            reinterpret_cast<f32x4*>(out + (size_t)rowBase * ROW_OUT);
#pragma unroll
        for (int k = t; k < (ROWS_PER_BLOCK * ROW_OUT) / 4; k += NTHREADS) {
            __builtin_nontemporal_store(tl4[k], &o4[k]);
        }
    } else {
        const int nout = nrows * ROW_OUT;
        for (int k = t; k < nout; k += NTHREADS) {
            out[(size_t)rowBase * ROW_OUT + k] = tile[k];
        }
    }
}

extern "C" void kernel_launch(void* const* d_in, const int* in_sizes, int n_in,
                              void* d_out, int out_size, void* d_ws, size_t ws_size,
                              hipStream_t stream) {
    const float* in = (const float*)d_in[0];
    float* out = (float*)d_out;
    const int B = in_sizes[0] / 63;
    const int blocks = (B + ROWS_PER_BLOCK - 1) / ROWS_PER_BLOCK;
    hipLaunchKernelGGL(HandKineticLayer_18545668784560_kernel,
                       dim3(blocks), dim3(NTHREADS), 0, stream,
                       in, out, B);
}

// Round 5
// 272.157 us; speedup vs baseline: 1.4295x; 1.0424x over previous
//
#include <hip/hip_runtime.h>
#include <math.h>

#define ROWS 16
#define NPAIRS 195
#define NTHREADS 256
#define ROW_OUT 258            // 63 copied + 195 distances
#define NLM 21
#define TILE_F (ROWS * ROW_OUT)   // 4128 floats = 16512 B (16B-aligned stride)
#define GRID 1024                 // 4 blocks/CU on 256 CUs

typedef float f32x4 __attribute__((ext_vector_type(4)));

// ---- compile-time pair table, packed as (i | j<<16) ----
struct CodeTab { unsigned int c[NPAIRS]; };

constexpr CodeTab make_codes() {
    CodeTab t{};
    int n = 0;
    for (int a = 0; a < 20; ++a) {
        bool tip = (a == 4) || (a == 8) || (a == 12) || (a == 16) || (a == 19);
        int start = tip ? a + 1 : a + 2;
        for (int b = start; b < 21; ++b) {
            t.c[n] = (unsigned int)a | ((unsigned int)b << 16);
            ++n;
        }
    }
    return t;
}

__constant__ CodeTab CODES = make_codes();

__device__ __forceinline__ void scatter_tile(float* __restrict__ tile,
                                             float2* __restrict__ xy2,
                                             const f32x4 v, int t) {
    const int f = t * 4;
#pragma unroll
    for (int e = 0; e < 4; ++e) {
        const int g = f + e;
        const int row = g / 63;
        const int col = g - row * 63;
        tile[row * ROW_OUT + col] = v[e];
        const int lm = col / 3;
        const int c3 = col - lm * 3;
        if (c3 == 0) xy2[row * NLM + lm].x = v[e];
        else if (c3 == 1) xy2[row * NLM + lm].y = v[e];
    }
}

__device__ __forceinline__ void compute_dists(float* __restrict__ tile,
                                              const float2* __restrict__ xy2,
                                              int t) {
#pragma unroll
    for (int k = 0; k < 13; ++k) {
        const int idx = t + k * NTHREADS;
        if (idx < ROWS * NPAIRS) {
            const int row = idx / NPAIRS;
            const int p = idx - row * NPAIRS;
            const unsigned int c = CODES.c[p];
            const float2 a = xy2[row * NLM + (int)(c & 0xffu)];
            const float2 b = xy2[row * NLM + (int)(c >> 16)];
            const float dx = a.x - b.x;
            const float dy = a.y - b.y;
            tile[row * ROW_OUT + 63 + p] = sqrtf(dx * dx + dy * dy);
        }
    }
}

// in : [B, 63]  (21 landmarks x (x,y,z))
// out: [B, 258] = [copy of 63 | 195 pairwise 2D distances]
__global__ __launch_bounds__(NTHREADS)
void HandKineticLayer_18545668784560_kernel(const float* __restrict__ in,
                                            float* __restrict__ out,
                                            int B) {
    __shared__ __align__(16) float tile[2][TILE_F];
    __shared__ float2 xy2[2][ROWS * NLM];

    const int t = threadIdx.x;
    const int ntiles = B / ROWS;               // full tiles

    // ---- prologue: load + scatter first tile into buffer 0 ----
    const int tile0 = blockIdx.x;
    if (tile0 < ntiles) {
        if (t < 252) {
            const f32x4* __restrict__ in4 =
                reinterpret_cast<const f32x4*>(in + (size_t)tile0 * (ROWS * 63));
            const f32x4 v = __builtin_nontemporal_load(&in4[t]);
            scatter_tile(tile[0], xy2[0], v, t);
        }
        __syncthreads();
    }

    // ---- pipelined main loop: prefetch(k+1) || compute(k); store(k); scatter(k+1) ----
    int i = 0;
    for (int tl = tile0; tl < ntiles; tl += GRID, ++i) {
        const int cur = i & 1;
        const int nxt = tl + GRID;
        f32x4 vn{};
        const bool have_next = (nxt < ntiles) && (t < 252);
        if (have_next) {
            const f32x4* __restrict__ in4 =
                reinterpret_cast<const f32x4*>(in + (size_t)nxt * (ROWS * 63));
            vn = __builtin_nontemporal_load(&in4[t]);   // in flight during compute+store
        }

        compute_dists(tile[cur], xy2[cur], t);
        __syncthreads();   // distances visible before store reads

        {
            const f32x4* __restrict__ tl4 =
                reinterpret_cast<const f32x4*>(&tile[cur][0]);
            f32x4* __restrict__ o4 =
                reinterpret_cast<f32x4*>(out + (size_t)tl * TILE_F);
#pragma unroll
            for (int k = t; k < TILE_F / 4; k += NTHREADS) {
                __builtin_nontemporal_store(tl4[k], &o4[k]);
            }
        }

        if (have_next) {
            scatter_tile(tile[cur ^ 1], xy2[cur ^ 1], vn, t);
        }
        __syncthreads();   // scatter visible for next compute; store reads drained
    }

    // ---- tail: partial tile (B % 16 != 0), one block, non-pipelined ----
    const int rem = B - ntiles * ROWS;
    if (rem > 0 && blockIdx.x == (unsigned)(ntiles % GRID)) {
        const int rowBase = ntiles * ROWS;
        const int nelem = rem * 63;
        for (int g = t; g < nelem; g += NTHREADS) {
            const float val = in[(size_t)rowBase * 63 + g];
            const int row = g / 63;
            const int col = g - row * 63;
            tile[0][row * ROW_OUT + col] = val;
            const int lm = col / 3;
            const int c3 = col - lm * 3;
            if (c3 == 0) xy2[0][row * NLM + lm].x = val;
            else if (c3 == 1) xy2[0][row * NLM + lm].y = val;
        }
        __syncthreads();
        const int total = rem * NPAIRS;
        for (int idx = t; idx < total; idx += NTHREADS) {
            const int row = idx / NPAIRS;
            const int p = idx - row * NPAIRS;
            const unsigned int c = CODES.c[p];
            const float2 a = xy2[0][row * NLM + (int)(c & 0xffu)];
            const float2 b = xy2[0][row * NLM + (int)(c >> 16)];
            const float dx = a.x - b.x;
            const float dy = a.y - b.y;
            tile[0][row * ROW_OUT + 63 + p] = sqrtf(dx * dx + dy * dy);
        }
        __syncthreads();
        const int nout = rem * ROW_OUT;
        for (int k = t; k < nout; k += NTHREADS) {
            out[(size_t)rowBase * ROW_OUT + k] = tile[0][k];
        }
    }
}

extern "C" void kernel_launch(void* const* d_in, const int* in_sizes, int n_in,
                              void* d_out, int out_size, void* d_ws, size_t ws_size,
                              hipStream_t stream) {
    const float* in = (const float*)d_in[0];
    float* out = (float*)d_out;
    const int B = in_sizes[0] / 63;
    hipLaunchKernelGGL(HandKineticLayer_18545668784560_kernel,
                       dim3(GRID), dim3(NTHREADS), 0, stream,
                       in, out, B);
}